// Round 8
// baseline (487.549 us; speedup 1.0000x reference)
//
#include <hip/hip_runtime.h>

static constexpr int NUSERS = 100000;
static constexpr int NITEMS = 50000;
static constexpr int NNODES = NUSERS + NITEMS;   // 150000
static constexpr int D      = 64;
static constexpr int NNZE   = 4800000;           // COO entries
static constexpr int NVEC4  = NNODES * D / 4;    // 2.4M 4-col groups
static constexpr int NU4    = NUSERS * D / 4;

static constexpr int NB       = 512;                       // buckets
static constexpr int RPB      = (NNODES + NB - 1) / NB;    // 293 rows/bucket
static constexpr int CHUNK    = 4096;                      // edges per part1 block
static constexpr int P1_BLOCKS = (NNZE + CHUNK - 1) / CHUNK; // 1172

__device__ __forceinline__ unsigned bf16rne(float f) {
    unsigned u = __float_as_uint(f);
    return (u + 0x7FFFu + ((u >> 16) & 1u)) >> 16;   // round-to-nearest-even bf16
}
__device__ __forceinline__ float bflo(unsigned u) { return __uint_as_float(u << 16); }
__device__ __forceinline__ float bfhi(unsigned u) { return __uint_as_float(u & 0xFFFF0000u); }

// ---------- stage: x = ego (packed bf16) ----------
__global__ void lg_init(const float4* __restrict__ ue, const float4* __restrict__ ie,
                        uint2* __restrict__ x) {
    int stride = gridDim.x * blockDim.x;
    for (int i = blockIdx.x * blockDim.x + threadIdx.x; i < NVEC4; i += stride) {
        float4 v = (i < NU4) ? ue[i] : ie[i - NU4];
        x[i] = make_uint2(bf16rne(v.x) | (bf16rne(v.y) << 16),
                          bf16rne(v.z) | (bf16rne(v.w) << 16));
    }
}

// ---------- bucket-level histogram: LDS-privatized, int4 loads ----------
__global__ void __launch_bounds__(512)
lg_bcnt(const int* __restrict__ rows, int* __restrict__ bucketCnt) {
    __shared__ int cnt[NB];
    int t = threadIdx.x;
    cnt[t] = 0;
    __syncthreads();
    int c0 = blockIdx.x * CHUNK;
    int c1 = min(c0 + CHUNK, NNZE);
    #pragma unroll
    for (int pass = 0; pass < 2; ++pass) {
        int e = c0 + (pass * 512 + t) * 4;
        if (e < c1) {   // c1 is a multiple of 4 -> whole int4 is in range
            int4 r4 = *(const int4*)(rows + e);
            atomicAdd(&cnt[r4.x / RPB], 1);
            atomicAdd(&cnt[r4.y / RPB], 1);
            atomicAdd(&cnt[r4.z / RPB], 1);
            atomicAdd(&cnt[r4.w / RPB], 1);
        }
    }
    __syncthreads();
    int n = cnt[t];
    if (n) atomicAdd(&bucketCnt[t], n);
}

// ---------- scan 512 bucket counts -> bbase[513]; seed gcur ----------
__global__ void __launch_bounds__(512)
lg_bscan(const int* __restrict__ bucketCnt, int* __restrict__ bbase,
         int* __restrict__ gcur) {
    __shared__ int s[NB];
    int t = threadIdx.x;
    int v = bucketCnt[t];
    s[t] = v;
    __syncthreads();
    for (int off = 1; off < NB; off <<= 1) {
        int tmp = (t >= off) ? s[t - off] : 0;
        __syncthreads();
        s[t] += tmp;
        __syncthreads();
    }
    int ex = s[t] - v;          // exclusive prefix
    bbase[t] = ex;
    gcur[t] = ex;
    if (t == NB - 1) bbase[NB] = s[t];
}

// ---------- phase 1: bucket partition with LDS-sorted staging ----------
__global__ void __launch_bounds__(512)
lg_part1(const int* __restrict__ rows, const int* __restrict__ cols,
         const float* __restrict__ vals, int* __restrict__ gcur,
         int2* __restrict__ stage) {
    __shared__ int s_cnt[NB];
    __shared__ int s_lcur[NB];
    __shared__ int s_gofs[NB];
    __shared__ int2 s_pay[CHUNK];
    __shared__ unsigned short s_bid[CHUNK];
    int t = threadIdx.x;
    int c0 = blockIdx.x * CHUNK;
    int c1 = min(c0 + CHUNK, NNZE);
    s_cnt[t] = 0;
    __syncthreads();

    int  eb[8], ep[8]; float ev[8];
    bool has0, has1;
    {
        int e = c0 + t * 4;
        has0 = e < c1;
        if (has0) {
            int4 r4 = *(const int4*)(rows + e);
            int4 c4 = *(const int4*)(cols + e);
            float4 v4 = *(const float4*)(vals + e);
            eb[0] = r4.x / RPB; ep[0] = c4.x | ((r4.x - eb[0] * RPB) << 18); ev[0] = v4.x;
            eb[1] = r4.y / RPB; ep[1] = c4.y | ((r4.y - eb[1] * RPB) << 18); ev[1] = v4.y;
            eb[2] = r4.z / RPB; ep[2] = c4.z | ((r4.z - eb[2] * RPB) << 18); ev[2] = v4.z;
            eb[3] = r4.w / RPB; ep[3] = c4.w | ((r4.w - eb[3] * RPB) << 18); ev[3] = v4.w;
            atomicAdd(&s_cnt[eb[0]], 1); atomicAdd(&s_cnt[eb[1]], 1);
            atomicAdd(&s_cnt[eb[2]], 1); atomicAdd(&s_cnt[eb[3]], 1);
        }
        e = c0 + (512 + t) * 4;
        has1 = e < c1;
        if (has1) {
            int4 r4 = *(const int4*)(rows + e);
            int4 c4 = *(const int4*)(cols + e);
            float4 v4 = *(const float4*)(vals + e);
            eb[4] = r4.x / RPB; ep[4] = c4.x | ((r4.x - eb[4] * RPB) << 18); ev[4] = v4.x;
            eb[5] = r4.y / RPB; ep[5] = c4.y | ((r4.y - eb[5] * RPB) << 18); ev[5] = v4.y;
            eb[6] = r4.z / RPB; ep[6] = c4.z | ((r4.z - eb[6] * RPB) << 18); ev[6] = v4.z;
            eb[7] = r4.w / RPB; ep[7] = c4.w | ((r4.w - eb[7] * RPB) << 18); ev[7] = v4.w;
            atomicAdd(&s_cnt[eb[4]], 1); atomicAdd(&s_cnt[eb[5]], 1);
            atomicAdd(&s_cnt[eb[6]], 1); atomicAdd(&s_cnt[eb[7]], 1);
        }
    }
    __syncthreads();

    int myCnt = s_cnt[t];
    for (int off = 1; off < NB; off <<= 1) {
        int tmp = (t >= off) ? s_cnt[t - off] : 0;
        __syncthreads();
        s_cnt[t] += tmp;
        __syncthreads();
    }
    int lstart = s_cnt[t] - myCnt;
    int gbase = myCnt ? atomicAdd(&gcur[t], myCnt) : 0;
    s_lcur[t] = lstart;
    s_gofs[t] = gbase - lstart;
    __syncthreads();

    #pragma unroll
    for (int k = 0; k < 4; ++k) {
        if (has0) {
            int pos = atomicAdd(&s_lcur[eb[k]], 1);
            s_pay[pos] = make_int2(ep[k], __float_as_int(ev[k]));
            s_bid[pos] = (unsigned short)eb[k];
        }
    }
    #pragma unroll
    for (int k = 4; k < 8; ++k) {
        if (has1) {
            int pos = atomicAdd(&s_lcur[eb[k]], 1);
            s_pay[pos] = make_int2(ep[k], __float_as_int(ev[k]));
            s_bid[pos] = (unsigned short)eb[k];
        }
    }
    __syncthreads();

    int n = c1 - c0;
    for (int p = t; p < n; p += 512) {
        int b = s_bid[p];
        stage[s_gofs[b] + p] = s_pay[p];
    }
}

// ---------- phase 2: per-bucket rowptr build + exact CSR placement ----------
__global__ void __launch_bounds__(512)
lg_part2(const int* __restrict__ bbase, const int2* __restrict__ stage,
         int2* __restrict__ csr, int* __restrict__ rowptr) {
    __shared__ int s[NB];
    __shared__ int lcur[RPB];
    int b = blockIdx.x;
    int t = threadIdx.x;
    int r0 = b * RPB;
    int nrows = min(RPB, NNODES - r0);
    int s0 = bbase[b], s1 = bbase[b + 1];

    s[t] = 0;
    __syncthreads();
    for (int p = s0 + t; p < s1; p += 512)
        atomicAdd(&s[(stage[p].x >> 18) & 511], 1);
    __syncthreads();
    int v = s[t];
    for (int off = 1; off < NB; off <<= 1) {
        int tmp = (t >= off) ? s[t - off] : 0;
        __syncthreads();
        s[t] += tmp;
        __syncthreads();
    }
    int pos0 = s0 + s[t] - v;
    if (t < nrows) {
        rowptr[r0 + t] = pos0;
        lcur[t] = pos0;
    }
    if (b == gridDim.x - 1 && t == 0) rowptr[NNODES] = NNZE;
    __syncthreads();
    for (int p = s0 + t; p < s1; p += 512) {
        int2 cv = stage[p];
        int rl = (cv.x >> 18) & 511;
        int pos = atomicAdd(&lcur[rl], 1);
        csr[pos] = make_int2(cv.x & 0x3FFFF, cv.y);
    }
}

// ---------- pull SpMM: 2 rows per 16-lane group, NT csr stream ----------
__device__ __forceinline__ void edge4(const long long* __restrict__ csr, int p,
                                      const uint2* __restrict__ x, int lane16,
                                      float4& acc) {
    long long cv0 = __builtin_nontemporal_load(csr + p);
    long long cv1 = __builtin_nontemporal_load(csr + p + 1);
    long long cv2 = __builtin_nontemporal_load(csr + p + 2);
    long long cv3 = __builtin_nontemporal_load(csr + p + 3);
    uint2 x0 = x[((int)cv0) * 16 + lane16];
    uint2 x1 = x[((int)cv1) * 16 + lane16];
    uint2 x2 = x[((int)cv2) * 16 + lane16];
    uint2 x3 = x[((int)cv3) * 16 + lane16];
    float v0 = __int_as_float((int)(cv0 >> 32)), v1 = __int_as_float((int)(cv1 >> 32));
    float v2 = __int_as_float((int)(cv2 >> 32)), v3 = __int_as_float((int)(cv3 >> 32));
    acc.x += v0 * bflo(x0.x) + v1 * bflo(x1.x) + v2 * bflo(x2.x) + v3 * bflo(x3.x);
    acc.y += v0 * bfhi(x0.x) + v1 * bfhi(x1.x) + v2 * bfhi(x2.x) + v3 * bfhi(x3.x);
    acc.z += v0 * bflo(x0.y) + v1 * bflo(x1.y) + v2 * bflo(x2.y) + v3 * bflo(x3.y);
    acc.w += v0 * bfhi(x0.y) + v1 * bfhi(x1.y) + v2 * bfhi(x2.y) + v3 * bfhi(x3.y);
}

__device__ __forceinline__ void edge1(const long long* __restrict__ csr, int p,
                                      const uint2* __restrict__ x, int lane16,
                                      float4& acc) {
    long long cv = __builtin_nontemporal_load(csr + p);
    uint2 xv = x[((int)cv) * 16 + lane16];
    float v = __int_as_float((int)(cv >> 32));
    acc.x += v * bflo(xv.x); acc.y += v * bfhi(xv.x);
    acc.z += v * bflo(xv.y); acc.w += v * bfhi(xv.y);
}

__global__ void __launch_bounds__(256)
lg_spmm(const int* __restrict__ rowptr, const long long* __restrict__ csr,
        const uint2* __restrict__ x, uint2* __restrict__ y) {
    int lane16 = threadIdx.x & 15;
    int g = (blockIdx.x * blockDim.x + threadIdx.x) >> 4;   // group = 2 rows
    if (g >= NNODES / 2) return;
    int r0 = 2 * g;
    int pa = rowptr[r0], pm = rowptr[r0 + 1], pe = rowptr[r0 + 2];
    float4 acc0 = {0.f, 0.f, 0.f, 0.f};
    float4 acc1 = {0.f, 0.f, 0.f, 0.f};
    int p0 = pa, p1 = pm;
    // lockstep: 8 independent gathers in flight
    while (p0 + 4 <= pm && p1 + 4 <= pe) {
        edge4(csr, p0, x, lane16, acc0);
        edge4(csr, p1, x, lane16, acc1);
        p0 += 4; p1 += 4;
    }
    for (; p0 + 4 <= pm; p0 += 4) edge4(csr, p0, x, lane16, acc0);
    for (; p1 + 4 <= pe; p1 += 4) edge4(csr, p1, x, lane16, acc1);
    for (; p0 < pm; ++p0) edge1(csr, p0, x, lane16, acc0);
    for (; p1 < pe; ++p1) edge1(csr, p1, x, lane16, acc1);

    long long o0 = (long long)(bf16rne(acc0.x) | (bf16rne(acc0.y) << 16)) |
                   ((long long)(bf16rne(acc0.z) | (bf16rne(acc0.w) << 16)) << 32);
    long long o1 = (long long)(bf16rne(acc1.x) | (bf16rne(acc1.y) << 16)) |
                   ((long long)(bf16rne(acc1.z) | (bf16rne(acc1.w) << 16)) << 32);
    __builtin_nontemporal_store(o0, (long long*)(y + r0 * 16 + lane16));
    __builtin_nontemporal_store(o1, (long long*)(y + (r0 + 1) * 16 + lane16));
}

// ---------- final combine: out = 0.25 * (ego_fp32 + y1 + y2 + y3) ----------
__global__ void lg_combine(const float4* __restrict__ ue, const float4* __restrict__ ie,
                           const uint2* __restrict__ y1, const uint2* __restrict__ y2,
                           const uint2* __restrict__ y3, float4* __restrict__ out) {
    int stride = gridDim.x * blockDim.x;
    for (int i = blockIdx.x * blockDim.x + threadIdx.x; i < NVEC4; i += stride) {
        float4 e = (i < NU4) ? ue[i] : ie[i - NU4];
        uint2 a = y1[i], b = y2[i], c = y3[i];
        float4 o;
        o.x = (e.x + bflo(a.x) + bflo(b.x) + bflo(c.x)) * 0.25f;
        o.y = (e.y + bfhi(a.x) + bfhi(b.x) + bfhi(c.x)) * 0.25f;
        o.z = (e.z + bflo(a.y) + bflo(b.y) + bflo(c.y)) * 0.25f;
        o.w = (e.w + bfhi(a.y) + bfhi(b.y) + bfhi(c.y)) * 0.25f;
        out[i] = o;
    }
}

extern "C" void kernel_launch(void* const* d_in, const int* in_sizes, int n_in,
                              void* d_out, int out_size, void* d_ws, size_t ws_size,
                              hipStream_t stream) {
    const float* ue   = (const float*)d_in[0];
    const float* ie   = (const float*)d_in[1];
    const float* vals = (const float*)d_in[2];
    const int*   rows = (const int*)d_in[3];
    const int*   cols = (const int*)d_in[4];
    float* out = (float*)d_out;

    // workspace (~115.8 MB)
    uint2* xa     = (uint2*)d_ws;                // 19.2 MB (bf16 ego -> y2)
    uint2* xb     = xa + NVEC4;                  // 19.2 MB (y1)
    int2*  csr    = (int2*)(xb + NVEC4);         // 38.4 MB
    int2*  stage  = csr + NNZE;                  // 38.4 MB (dead after part2)
    uint2* y3     = (uint2*)stage;               // 19.2 MB alias onto stage
    int*   rowptr = (int*)(stage + NNZE);        // 150001 ints
    int*   bucketCnt = rowptr + (NNODES + 1);    // 512
    int*   bbase  = bucketCnt + NB;              // 513
    int*   gcur   = bbase + (NB + 1);            // 512

    const int spmmBlocks = (NNODES / 2 * 16 + 255) / 256;  // 4688

    lg_init<<<2048, 256, 0, stream>>>((const float4*)ue, (const float4*)ie, xa);
    hipMemsetAsync(bucketCnt, 0, NB * sizeof(int), stream);
    lg_bcnt<<<P1_BLOCKS, 512, 0, stream>>>(rows, bucketCnt);
    lg_bscan<<<1, NB, 0, stream>>>(bucketCnt, bbase, gcur);
    lg_part1<<<P1_BLOCKS, 512, 0, stream>>>(rows, cols, vals, gcur, stage);
    lg_part2<<<NB, 512, 0, stream>>>(bbase, stage, csr, rowptr);

    lg_spmm<<<spmmBlocks, 256, 0, stream>>>(rowptr, (const long long*)csr, xa, xb);
    lg_spmm<<<spmmBlocks, 256, 0, stream>>>(rowptr, (const long long*)csr, xb, xa);
    lg_spmm<<<spmmBlocks, 256, 0, stream>>>(rowptr, (const long long*)csr, xa, y3);

    lg_combine<<<2048, 256, 0, stream>>>((const float4*)ue, (const float4*)ie,
                                         xb, xa, y3, (float4*)out);
}

// Round 9
// 368.628 us; speedup vs baseline: 1.3226x; 1.3226x over previous
//
#include <hip/hip_runtime.h>

static constexpr int NUSERS = 100000;
static constexpr int NITEMS = 50000;
static constexpr int NNODES = NUSERS + NITEMS;   // 150000
static constexpr int D      = 64;
static constexpr int NNZE   = 4800000;           // COO entries
static constexpr int NVEC4  = NNODES * D / 4;    // 2.4M 4-col groups
static constexpr int NU4    = NUSERS * D / 4;

static constexpr int NB       = 512;                       // buckets
static constexpr int RPB      = (NNODES + NB - 1) / NB;    // 293 rows/bucket
static constexpr int CHUNK    = 4096;                      // edges per part1 block
static constexpr int P1_BLOCKS = (NNZE + CHUNK - 1) / CHUNK; // 1172

__device__ __forceinline__ unsigned bf16rne(float f) {
    unsigned u = __float_as_uint(f);
    return (u + 0x7FFFu + ((u >> 16) & 1u)) >> 16;   // round-to-nearest-even bf16
}
__device__ __forceinline__ float bflo(unsigned u) { return __uint_as_float(u << 16); }
__device__ __forceinline__ float bfhi(unsigned u) { return __uint_as_float(u & 0xFFFF0000u); }

// ---------- stage: x = ego (packed bf16) ----------
__global__ void lg_init(const float4* __restrict__ ue, const float4* __restrict__ ie,
                        uint2* __restrict__ x) {
    int stride = gridDim.x * blockDim.x;
    for (int i = blockIdx.x * blockDim.x + threadIdx.x; i < NVEC4; i += stride) {
        float4 v = (i < NU4) ? ue[i] : ie[i - NU4];
        x[i] = make_uint2(bf16rne(v.x) | (bf16rne(v.y) << 16),
                          bf16rne(v.z) | (bf16rne(v.w) << 16));
    }
}

// ---------- bucket-level histogram: LDS-privatized, int4 loads ----------
__global__ void __launch_bounds__(512)
lg_bcnt(const int* __restrict__ rows, int* __restrict__ bucketCnt) {
    __shared__ int cnt[NB];
    int t = threadIdx.x;
    cnt[t] = 0;
    __syncthreads();
    int c0 = blockIdx.x * CHUNK;
    int c1 = min(c0 + CHUNK, NNZE);
    #pragma unroll
    for (int pass = 0; pass < 2; ++pass) {
        int e = c0 + (pass * 512 + t) * 4;
        if (e < c1) {
            int4 r4 = *(const int4*)(rows + e);
            atomicAdd(&cnt[r4.x / RPB], 1);
            atomicAdd(&cnt[r4.y / RPB], 1);
            atomicAdd(&cnt[r4.z / RPB], 1);
            atomicAdd(&cnt[r4.w / RPB], 1);
        }
    }
    __syncthreads();
    int n = cnt[t];
    if (n) atomicAdd(&bucketCnt[t], n);
}

// ---------- scan 512 bucket counts -> bbase[513]; seed gcur ----------
__global__ void __launch_bounds__(512)
lg_bscan(const int* __restrict__ bucketCnt, int* __restrict__ bbase,
         int* __restrict__ gcur) {
    __shared__ int s[NB];
    int t = threadIdx.x;
    int v = bucketCnt[t];
    s[t] = v;
    __syncthreads();
    for (int off = 1; off < NB; off <<= 1) {
        int tmp = (t >= off) ? s[t - off] : 0;
        __syncthreads();
        s[t] += tmp;
        __syncthreads();
    }
    int ex = s[t] - v;          // exclusive prefix
    bbase[t] = ex;
    gcur[t] = ex;
    if (t == NB - 1) bbase[NB] = s[t];
}

// ---------- phase 1: bucket partition with LDS-sorted staging ----------
__global__ void __launch_bounds__(512)
lg_part1(const int* __restrict__ rows, const int* __restrict__ cols,
         const float* __restrict__ vals, int* __restrict__ gcur,
         int2* __restrict__ stage) {
    __shared__ int s_cnt[NB];
    __shared__ int s_lcur[NB];
    __shared__ int s_gofs[NB];
    __shared__ int2 s_pay[CHUNK];
    __shared__ unsigned short s_bid[CHUNK];
    int t = threadIdx.x;
    int c0 = blockIdx.x * CHUNK;
    int c1 = min(c0 + CHUNK, NNZE);
    s_cnt[t] = 0;
    __syncthreads();

    int  eb[8], ep[8]; float ev[8];
    bool has0, has1;
    {
        int e = c0 + t * 4;
        has0 = e < c1;
        if (has0) {
            int4 r4 = *(const int4*)(rows + e);
            int4 c4 = *(const int4*)(cols + e);
            float4 v4 = *(const float4*)(vals + e);
            eb[0] = r4.x / RPB; ep[0] = c4.x | ((r4.x - eb[0] * RPB) << 18); ev[0] = v4.x;
            eb[1] = r4.y / RPB; ep[1] = c4.y | ((r4.y - eb[1] * RPB) << 18); ev[1] = v4.y;
            eb[2] = r4.z / RPB; ep[2] = c4.z | ((r4.z - eb[2] * RPB) << 18); ev[2] = v4.z;
            eb[3] = r4.w / RPB; ep[3] = c4.w | ((r4.w - eb[3] * RPB) << 18); ev[3] = v4.w;
            atomicAdd(&s_cnt[eb[0]], 1); atomicAdd(&s_cnt[eb[1]], 1);
            atomicAdd(&s_cnt[eb[2]], 1); atomicAdd(&s_cnt[eb[3]], 1);
        }
        e = c0 + (512 + t) * 4;
        has1 = e < c1;
        if (has1) {
            int4 r4 = *(const int4*)(rows + e);
            int4 c4 = *(const int4*)(cols + e);
            float4 v4 = *(const float4*)(vals + e);
            eb[4] = r4.x / RPB; ep[4] = c4.x | ((r4.x - eb[4] * RPB) << 18); ev[4] = v4.x;
            eb[5] = r4.y / RPB; ep[5] = c4.y | ((r4.y - eb[5] * RPB) << 18); ev[5] = v4.y;
            eb[6] = r4.z / RPB; ep[6] = c4.z | ((r4.z - eb[6] * RPB) << 18); ev[6] = v4.z;
            eb[7] = r4.w / RPB; ep[7] = c4.w | ((r4.w - eb[7] * RPB) << 18); ev[7] = v4.w;
            atomicAdd(&s_cnt[eb[4]], 1); atomicAdd(&s_cnt[eb[5]], 1);
            atomicAdd(&s_cnt[eb[6]], 1); atomicAdd(&s_cnt[eb[7]], 1);
        }
    }
    __syncthreads();

    int myCnt = s_cnt[t];
    for (int off = 1; off < NB; off <<= 1) {
        int tmp = (t >= off) ? s_cnt[t - off] : 0;
        __syncthreads();
        s_cnt[t] += tmp;
        __syncthreads();
    }
    int lstart = s_cnt[t] - myCnt;
    int gbase = myCnt ? atomicAdd(&gcur[t], myCnt) : 0;
    s_lcur[t] = lstart;
    s_gofs[t] = gbase - lstart;
    __syncthreads();

    #pragma unroll
    for (int k = 0; k < 4; ++k) {
        if (has0) {
            int pos = atomicAdd(&s_lcur[eb[k]], 1);
            s_pay[pos] = make_int2(ep[k], __float_as_int(ev[k]));
            s_bid[pos] = (unsigned short)eb[k];
        }
    }
    #pragma unroll
    for (int k = 4; k < 8; ++k) {
        if (has1) {
            int pos = atomicAdd(&s_lcur[eb[k]], 1);
            s_pay[pos] = make_int2(ep[k], __float_as_int(ev[k]));
            s_bid[pos] = (unsigned short)eb[k];
        }
    }
    __syncthreads();

    int n = c1 - c0;
    for (int p = t; p < n; p += 512) {
        int b = s_bid[p];
        stage[s_gofs[b] + p] = s_pay[p];
    }
}

// ---------- phase 2: per-bucket rowptr build + exact CSR placement ----------
__global__ void __launch_bounds__(512)
lg_part2(const int* __restrict__ bbase, const int2* __restrict__ stage,
         int2* __restrict__ csr, int* __restrict__ rowptr) {
    __shared__ int s[NB];
    __shared__ int lcur[RPB];
    int b = blockIdx.x;
    int t = threadIdx.x;
    int r0 = b * RPB;
    int nrows = min(RPB, NNODES - r0);
    int s0 = bbase[b], s1 = bbase[b + 1];

    s[t] = 0;
    __syncthreads();
    for (int p = s0 + t; p < s1; p += 512)
        atomicAdd(&s[(stage[p].x >> 18) & 511], 1);
    __syncthreads();
    int v = s[t];
    for (int off = 1; off < NB; off <<= 1) {
        int tmp = (t >= off) ? s[t - off] : 0;
        __syncthreads();
        s[t] += tmp;
        __syncthreads();
    }
    int pos0 = s0 + s[t] - v;
    if (t < nrows) {
        rowptr[r0 + t] = pos0;
        lcur[t] = pos0;
    }
    if (b == gridDim.x - 1 && t == 0) rowptr[NNODES] = NNZE;
    __syncthreads();
    for (int p = s0 + t; p < s1; p += 512) {
        int2 cv = stage[p];
        int rl = (cv.x >> 18) & 511;
        int pos = atomicAdd(&lcur[rl], 1);
        csr[pos] = make_int2(cv.x & 0x3FFFF, cv.y);
    }
}

// ---------- pull SpMM: 1 row per 16-lane group, unroll-8, cached loads ----------
__global__ void __launch_bounds__(256)
lg_spmm(const int* __restrict__ rowptr, const long long* __restrict__ csr,
        const uint2* __restrict__ x, uint2* __restrict__ y) {
    int lane16 = threadIdx.x & 15;
    int r = (blockIdx.x * blockDim.x + threadIdx.x) >> 4;
    if (r >= NNODES) return;
    int p0 = rowptr[r], p1 = rowptr[r + 1];
    float4 acc = {0.f, 0.f, 0.f, 0.f};
    int p = p0;
    // unroll-8: 8 independent csr loads + 8 independent x-gathers in flight
    for (; p + 8 <= p1; p += 8) {
        long long cv0 = csr[p],     cv1 = csr[p + 1], cv2 = csr[p + 2], cv3 = csr[p + 3];
        long long cv4 = csr[p + 4], cv5 = csr[p + 5], cv6 = csr[p + 6], cv7 = csr[p + 7];
        uint2 x0 = x[((int)cv0) * 16 + lane16];
        uint2 x1 = x[((int)cv1) * 16 + lane16];
        uint2 x2 = x[((int)cv2) * 16 + lane16];
        uint2 x3 = x[((int)cv3) * 16 + lane16];
        uint2 x4 = x[((int)cv4) * 16 + lane16];
        uint2 x5 = x[((int)cv5) * 16 + lane16];
        uint2 x6 = x[((int)cv6) * 16 + lane16];
        uint2 x7 = x[((int)cv7) * 16 + lane16];
        float v0 = __int_as_float((int)(cv0 >> 32)), v1 = __int_as_float((int)(cv1 >> 32));
        float v2 = __int_as_float((int)(cv2 >> 32)), v3 = __int_as_float((int)(cv3 >> 32));
        float v4 = __int_as_float((int)(cv4 >> 32)), v5 = __int_as_float((int)(cv5 >> 32));
        float v6 = __int_as_float((int)(cv6 >> 32)), v7 = __int_as_float((int)(cv7 >> 32));
        acc.x += v0 * bflo(x0.x) + v1 * bflo(x1.x) + v2 * bflo(x2.x) + v3 * bflo(x3.x)
               + v4 * bflo(x4.x) + v5 * bflo(x5.x) + v6 * bflo(x6.x) + v7 * bflo(x7.x);
        acc.y += v0 * bfhi(x0.x) + v1 * bfhi(x1.x) + v2 * bfhi(x2.x) + v3 * bfhi(x3.x)
               + v4 * bfhi(x4.x) + v5 * bfhi(x5.x) + v6 * bfhi(x6.x) + v7 * bfhi(x7.x);
        acc.z += v0 * bflo(x0.y) + v1 * bflo(x1.y) + v2 * bflo(x2.y) + v3 * bflo(x3.y)
               + v4 * bflo(x4.y) + v5 * bflo(x5.y) + v6 * bflo(x6.y) + v7 * bflo(x7.y);
        acc.w += v0 * bfhi(x0.y) + v1 * bfhi(x1.y) + v2 * bfhi(x2.y) + v3 * bfhi(x3.y)
               + v4 * bfhi(x4.y) + v5 * bfhi(x5.y) + v6 * bfhi(x6.y) + v7 * bfhi(x7.y);
    }
    for (; p + 4 <= p1; p += 4) {
        long long cv0 = csr[p], cv1 = csr[p + 1], cv2 = csr[p + 2], cv3 = csr[p + 3];
        uint2 x0 = x[((int)cv0) * 16 + lane16];
        uint2 x1 = x[((int)cv1) * 16 + lane16];
        uint2 x2 = x[((int)cv2) * 16 + lane16];
        uint2 x3 = x[((int)cv3) * 16 + lane16];
        float v0 = __int_as_float((int)(cv0 >> 32)), v1 = __int_as_float((int)(cv1 >> 32));
        float v2 = __int_as_float((int)(cv2 >> 32)), v3 = __int_as_float((int)(cv3 >> 32));
        acc.x += v0 * bflo(x0.x) + v1 * bflo(x1.x) + v2 * bflo(x2.x) + v3 * bflo(x3.x);
        acc.y += v0 * bfhi(x0.x) + v1 * bfhi(x1.x) + v2 * bfhi(x2.x) + v3 * bfhi(x3.x);
        acc.z += v0 * bflo(x0.y) + v1 * bflo(x1.y) + v2 * bflo(x2.y) + v3 * bflo(x3.y);
        acc.w += v0 * bfhi(x0.y) + v1 * bfhi(x1.y) + v2 * bfhi(x2.y) + v3 * bfhi(x3.y);
    }
    for (; p < p1; ++p) {
        long long cv = csr[p];
        uint2 xv = x[((int)cv) * 16 + lane16];
        float v = __int_as_float((int)(cv >> 32));
        acc.x += v * bflo(xv.x); acc.y += v * bfhi(xv.x);
        acc.z += v * bflo(xv.y); acc.w += v * bfhi(xv.y);
    }
    y[r * 16 + lane16] = make_uint2(bf16rne(acc.x) | (bf16rne(acc.y) << 16),
                                    bf16rne(acc.z) | (bf16rne(acc.w) << 16));
}

// ---------- final combine: out = 0.25 * (ego_fp32 + y1 + y2 + y3) ----------
__global__ void lg_combine(const float4* __restrict__ ue, const float4* __restrict__ ie,
                           const uint2* __restrict__ y1, const uint2* __restrict__ y2,
                           const uint2* __restrict__ y3, float4* __restrict__ out) {
    int stride = gridDim.x * blockDim.x;
    for (int i = blockIdx.x * blockDim.x + threadIdx.x; i < NVEC4; i += stride) {
        float4 e = (i < NU4) ? ue[i] : ie[i - NU4];
        uint2 a = y1[i], b = y2[i], c = y3[i];
        float4 o;
        o.x = (e.x + bflo(a.x) + bflo(b.x) + bflo(c.x)) * 0.25f;
        o.y = (e.y + bfhi(a.x) + bfhi(b.x) + bfhi(c.x)) * 0.25f;
        o.z = (e.z + bflo(a.y) + bflo(b.y) + bflo(c.y)) * 0.25f;
        o.w = (e.w + bfhi(a.y) + bfhi(b.y) + bfhi(c.y)) * 0.25f;
        out[i] = o;
    }
}

extern "C" void kernel_launch(void* const* d_in, const int* in_sizes, int n_in,
                              void* d_out, int out_size, void* d_ws, size_t ws_size,
                              hipStream_t stream) {
    const float* ue   = (const float*)d_in[0];
    const float* ie   = (const float*)d_in[1];
    const float* vals = (const float*)d_in[2];
    const int*   rows = (const int*)d_in[3];
    const int*   cols = (const int*)d_in[4];
    float* out = (float*)d_out;

    // workspace (~115.8 MB)
    uint2* xa     = (uint2*)d_ws;                // 19.2 MB (bf16 ego -> y2)
    uint2* xb     = xa + NVEC4;                  // 19.2 MB (y1)
    int2*  csr    = (int2*)(xb + NVEC4);         // 38.4 MB
    int2*  stage  = csr + NNZE;                  // 38.4 MB (dead after part2)
    uint2* y3     = (uint2*)stage;               // 19.2 MB alias onto stage
    int*   rowptr = (int*)(stage + NNZE);        // 150001 ints
    int*   bucketCnt = rowptr + (NNODES + 1);    // 512
    int*   bbase  = bucketCnt + NB;              // 513
    int*   gcur   = bbase + (NB + 1);            // 512

    const int spmmBlocks = NNODES * 16 / 256;    // 9375

    lg_init<<<2048, 256, 0, stream>>>((const float4*)ue, (const float4*)ie, xa);
    hipMemsetAsync(bucketCnt, 0, NB * sizeof(int), stream);
    lg_bcnt<<<P1_BLOCKS, 512, 0, stream>>>(rows, bucketCnt);
    lg_bscan<<<1, NB, 0, stream>>>(bucketCnt, bbase, gcur);
    lg_part1<<<P1_BLOCKS, 512, 0, stream>>>(rows, cols, vals, gcur, stage);
    lg_part2<<<NB, 512, 0, stream>>>(bbase, stage, csr, rowptr);

    lg_spmm<<<spmmBlocks, 256, 0, stream>>>(rowptr, (const long long*)csr, xa, xb);
    lg_spmm<<<spmmBlocks, 256, 0, stream>>>(rowptr, (const long long*)csr, xb, xa);
    lg_spmm<<<spmmBlocks, 256, 0, stream>>>(rowptr, (const long long*)csr, xa, y3);

    lg_combine<<<2048, 256, 0, stream>>>((const float4*)ue, (const float4*)ie,
                                         xb, xa, y3, (float4*)out);
}